// Round 1
// baseline (2751.237 us; speedup 1.0000x reference)
//
#include <hip/hip_runtime.h>
#include <hip/hip_bf16.h>

// Scatter-add message passing:
//   out[dst[e], :] += x[src[e], :]   for e in [0, E)
// x: [N, 128] fp32; edge_index: [2, E] int32 (row 0 = dst, row 1 = src).
// Baseline: 1 thread per (edge, 4-feature chunk); float4 gather + 4 fp32
// hardware atomics into L2. out zeroed via hipMemsetAsync (harness poisons it).

#define D_FEAT 128

__global__ void __launch_bounds__(256)
mp_scatter_add_kernel(const float* __restrict__ x,
                      const int* __restrict__ edge_dst,
                      const int* __restrict__ edge_src,
                      float* __restrict__ out,
                      int n_edges) {
    // Each thread: one edge e, one 16-byte feature chunk d4 (32 chunks/row).
    long long tid = (long long)blockIdx.x * blockDim.x + threadIdx.x;
    long long total = (long long)n_edges * (D_FEAT / 4);
    if (tid >= total) return;

    int e  = (int)(tid >> 5);   // tid / 32
    int d4 = (int)(tid & 31);   // tid % 32

    int src = edge_src[e];
    int dst = edge_dst[e];

    const float4 v = *reinterpret_cast<const float4*>(
        x + (long long)src * D_FEAT + d4 * 4);

    float* o = out + (long long)dst * D_FEAT + d4 * 4;
    atomicAdd(o + 0, v.x);
    atomicAdd(o + 1, v.y);
    atomicAdd(o + 2, v.z);
    atomicAdd(o + 3, v.w);
}

extern "C" void kernel_launch(void* const* d_in, const int* in_sizes, int n_in,
                              void* d_out, int out_size, void* d_ws, size_t ws_size,
                              hipStream_t stream) {
    const float* x        = (const float*)d_in[0];
    const int*   edge_idx = (const int*)d_in[1];

    const int n_edges = in_sizes[1] / 2;          // [2, E] flattened
    const int* edge_dst = edge_idx;               // edge_index[0]
    const int* edge_src = edge_idx + n_edges;     // edge_index[1]

    float* out = (float*)d_out;

    // Harness re-poisons d_out to 0xAA before every timed launch — zero it.
    hipMemsetAsync(out, 0, (size_t)out_size * sizeof(float), stream);

    const long long total = (long long)n_edges * (D_FEAT / 4);
    const int block = 256;
    const long long grid = (total + block - 1) / block;

    mp_scatter_add_kernel<<<(dim3)(unsigned)grid, block, 0, stream>>>(
        x, edge_dst, edge_src, out, n_edges);
}

// Round 5
// 645.725 us; speedup vs baseline: 4.2607x; 4.2607x over previous
//
#include <hip/hip_runtime.h>
#include <hip/hip_bf16.h>

// Scatter-add message passing via on-device counting-sort (CSR) + gather:
//   out[i,:] = sum_{e: dst[e]==i} x[src[e],:]
// x: [N,128] fp32; edge_index: [2,E] int32 (row 0 = dst, row 1 = src).
//
// Phase A: histogram of dst               (int atomics, 50k bins)
// Phase B: exclusive scan -> row_start    (single 1024-thread block)
// Phase C: bucket scatter of src indices  (int atomics on cursors)
// Phase D: per-node gather-sum, out written exactly once (no fp atomics)

#define DFEAT 128
#define SCAN_THREADS 1024

__global__ void __launch_bounds__(256)
hist_kernel(const int* __restrict__ dst, int* __restrict__ count, int E) {
    int stride = gridDim.x * blockDim.x;
    for (int e = blockIdx.x * blockDim.x + threadIdx.x; e < E; e += stride)
        atomicAdd(&count[dst[e]], 1);
}

__global__ void __launch_bounds__(SCAN_THREADS)
scan_kernel(int* __restrict__ count /*[N+1], in: counts, out: row_start*/,
            int* __restrict__ cursor /*[N]*/, int N) {
    __shared__ int sums[SCAN_THREADS];
    const int t = threadIdx.x;
    const int items = (N + SCAN_THREADS - 1) / SCAN_THREADS;
    const int beg = t * items;
    const int end = min(beg + items, N);

    int s = 0;
    for (int i = beg; i < end; ++i) s += count[i];
    sums[t] = s;
    __syncthreads();

    // Hillis-Steele inclusive scan over the 1024 thread sums.
    for (int off = 1; off < SCAN_THREADS; off <<= 1) {
        int v = (t >= off) ? sums[t - off] : 0;
        __syncthreads();
        sums[t] += v;
        __syncthreads();
    }

    int run = (t == 0) ? 0 : sums[t - 1];   // exclusive prefix of this chunk
    for (int i = beg; i < end; ++i) {
        int c = count[i];
        count[i]  = run;    // row_start[i]
        cursor[i] = run;
        run += c;
    }
    if (t == SCAN_THREADS - 1) count[N] = run;   // == E
}

__global__ void __launch_bounds__(256)
scatter_kernel(const int* __restrict__ dst, const int* __restrict__ src,
               int* __restrict__ cursor, int* __restrict__ sorted_src, int E) {
    int stride = gridDim.x * blockDim.x;
    for (int e = blockIdx.x * blockDim.x + threadIdx.x; e < E; e += stride) {
        int d = dst[e];
        int pos = atomicAdd(&cursor[d], 1);
        sorted_src[pos] = src[e];
    }
}

__global__ void __launch_bounds__(256)
gather_kernel(const float* __restrict__ x, const int* __restrict__ row_start,
              const int* __restrict__ sorted_src, float* __restrict__ out, int N) {
    // 2 nodes per 256-thread block; 128 threads per node, one column each.
    int node = blockIdx.x * 2 + (threadIdx.x >> 7);
    int c    = threadIdx.x & 127;
    if (node >= N) return;

    int beg = row_start[node];
    int end = row_start[node + 1];

    float acc = 0.f;
    for (int k = beg; k < end; ++k) {
        int s = sorted_src[k];                       // broadcast load
        acc += x[(long long)s * DFEAT + c];          // 512B coalesced row read
    }
    out[(long long)node * DFEAT + c] = acc;          // written exactly once
}

// ---- fallback (round-1 atomic version) if workspace is too small ----
__global__ void __launch_bounds__(256)
mp_scatter_add_kernel(const float* __restrict__ x,
                      const int* __restrict__ edge_dst,
                      const int* __restrict__ edge_src,
                      float* __restrict__ out, int n_edges) {
    long long tid = (long long)blockIdx.x * blockDim.x + threadIdx.x;
    long long total = (long long)n_edges * (DFEAT / 4);
    if (tid >= total) return;
    int e  = (int)(tid >> 5);
    int d4 = (int)(tid & 31);
    int src = edge_src[e];
    int dst = edge_dst[e];
    const float4 v = *reinterpret_cast<const float4*>(x + (long long)src * DFEAT + d4 * 4);
    float* o = out + (long long)dst * DFEAT + d4 * 4;
    atomicAdd(o + 0, v.x); atomicAdd(o + 1, v.y);
    atomicAdd(o + 2, v.z); atomicAdd(o + 3, v.w);
}

extern "C" void kernel_launch(void* const* d_in, const int* in_sizes, int n_in,
                              void* d_out, int out_size, void* d_ws, size_t ws_size,
                              hipStream_t stream) {
    const float* x        = (const float*)d_in[0];
    const int*   edge_idx = (const int*)d_in[1];

    const int N = in_sizes[0] / DFEAT;         // 50000
    const int E = in_sizes[1] / 2;             // 1600000
    const int* edge_dst = edge_idx;            // edge_index[0]
    const int* edge_src = edge_idx + E;        // edge_index[1]
    float* out = (float*)d_out;

    // Workspace layout (ints): row_start[N+1] | cursor[N] | sorted_src[E]
    const size_t need = (size_t)(2 * N + 2 + E) * sizeof(int);
    if (ws_size < need) {
        // Fallback: atomic scatter-add.
        (void)hipMemsetAsync(out, 0, (size_t)out_size * sizeof(float), stream);
        const long long total = (long long)E * (DFEAT / 4);
        const long long grid = (total + 255) / 256;
        mp_scatter_add_kernel<<<(dim3)(unsigned)grid, 256, 0, stream>>>(
            x, edge_dst, edge_src, out, E);
        return;
    }

    int* row_start  = (int*)d_ws;              // N+1
    int* cursor     = row_start + (N + 1);     // N
    int* sorted_src = cursor + N;              // E

    (void)hipMemsetAsync(row_start, 0, (size_t)(N + 1) * sizeof(int), stream);

    hist_kernel   <<<2048, 256, 0, stream>>>(edge_dst, row_start, E);
    scan_kernel   <<<1, SCAN_THREADS, 0, stream>>>(row_start, cursor, N);
    scatter_kernel<<<2048, 256, 0, stream>>>(edge_dst, edge_src, cursor, sorted_src, E);

    const int gather_blocks = (N + 1) / 2;     // 2 nodes / block
    gather_kernel<<<gather_blocks, 256, 0, stream>>>(x, row_start, sorted_src, out, N);
}

// Round 6
// 375.098 us; speedup vs baseline: 7.3347x; 1.7215x over previous
//
#include <hip/hip_runtime.h>
#include <hip/hip_bf16.h>

// Scatter-add message passing via on-device counting-sort (CSR) + gather:
//   out[i,:] = sum_{e: dst[e]==i} x[src[e],:]
// x: [N,128] fp32; edge_index: [2,E] int32 (row 0 = dst, row 1 = src).
//
// A: histogram of dst (int4 reads, int atomics)
// B: parallel 3-phase exclusive scan -> row_start (+cursor copy)
// C: bucket scatter of src (int4 reads, atomic cursors)
// D: gather v2 — 1 wave/node, float2/lane, shfl-broadcast indices, 4x unroll

#define DFEAT 128

__global__ void __launch_bounds__(256)
hist_kernel(const int* __restrict__ dst, int* __restrict__ count, int E) {
    const int tid = blockIdx.x * blockDim.x + threadIdx.x;
    const int stride = gridDim.x * blockDim.x;
    const int4* d4 = (const int4*)dst;
    const int E4 = E >> 2;
    for (int e = tid; e < E4; e += stride) {
        int4 v = d4[e];
        atomicAdd(&count[v.x], 1); atomicAdd(&count[v.y], 1);
        atomicAdd(&count[v.z], 1); atomicAdd(&count[v.w], 1);
    }
    for (int e = (E4 << 2) + tid; e < E; e += stride)
        atomicAdd(&count[dst[e]], 1);
}

// --- parallel scan: partial sums -> scan block sums -> apply ---
__global__ void __launch_bounds__(256)
scan_partial_kernel(const int* __restrict__ count, int* __restrict__ blocksum, int N) {
    __shared__ int s[256];
    const int t = threadIdx.x;
    const int i = blockIdx.x * 256 + t;
    s[t] = (i < N) ? count[i] : 0;
    __syncthreads();
    for (int off = 128; off > 0; off >>= 1) {
        if (t < off) s[t] += s[t + off];
        __syncthreads();
    }
    if (t == 0) blocksum[blockIdx.x] = s[0];
}

__global__ void __launch_bounds__(256)
scan_blocksum_kernel(int* __restrict__ blocksum, int* __restrict__ total, int nb) {
    __shared__ int s[256];
    const int t = threadIdx.x;
    s[t] = (t < nb) ? blocksum[t] : 0;
    __syncthreads();
    for (int off = 1; off < 256; off <<= 1) {
        int u = (t >= off) ? s[t - off] : 0;
        __syncthreads();
        s[t] += u;
        __syncthreads();
    }
    int excl = (t == 0) ? 0 : s[t - 1];
    if (t < nb) blocksum[t] = excl;
    if (t == 255) *total = s[255];   // row_start[N] = E
}

__global__ void __launch_bounds__(256)
scan_apply_kernel(int* __restrict__ count /*in: counts, out: row_start*/,
                  const int* __restrict__ blocksum,
                  int* __restrict__ cursor, int N) {
    __shared__ int s[256];
    const int t = threadIdx.x;
    const int i = blockIdx.x * 256 + t;
    int v = (i < N) ? count[i] : 0;
    s[t] = v;
    __syncthreads();
    for (int off = 1; off < 256; off <<= 1) {
        int u = (t >= off) ? s[t - off] : 0;
        __syncthreads();
        s[t] += u;
        __syncthreads();
    }
    int excl = blocksum[blockIdx.x] + ((t == 0) ? 0 : s[t - 1]);
    if (i < N) { count[i] = excl; cursor[i] = excl; }
}

__global__ void __launch_bounds__(256)
scatter_kernel(const int* __restrict__ dst, const int* __restrict__ src,
               int* __restrict__ cursor, int* __restrict__ sorted_src, int E) {
    const int tid = blockIdx.x * blockDim.x + threadIdx.x;
    const int stride = gridDim.x * blockDim.x;
    const int4* d4 = (const int4*)dst;
    const int4* s4 = (const int4*)src;
    const int E4 = E >> 2;
    for (int e = tid; e < E4; e += stride) {
        int4 d = d4[e];
        int4 s = s4[e];
        sorted_src[atomicAdd(&cursor[d.x], 1)] = s.x;
        sorted_src[atomicAdd(&cursor[d.y], 1)] = s.y;
        sorted_src[atomicAdd(&cursor[d.z], 1)] = s.z;
        sorted_src[atomicAdd(&cursor[d.w], 1)] = s.w;
    }
    for (int e = (E4 << 2) + tid; e < E; e += stride) {
        int d = dst[e];
        sorted_src[atomicAdd(&cursor[d], 1)] = src[e];
    }
}

__global__ void __launch_bounds__(256)
gather_kernel(const float* __restrict__ x, const int* __restrict__ row_start,
              const int* __restrict__ sorted_src, float* __restrict__ out, int N) {
    // 1 wave (64 lanes) per node; each lane owns 2 columns (float2 = 8B).
    // Indices fetched 64-at-a-time coalesced, broadcast via __shfl.
    const int wid  = threadIdx.x >> 6;           // wave in block (0..3)
    const int lane = threadIdx.x & 63;
    const int node = blockIdx.x * 4 + wid;
    if (node >= N) return;

    const int beg = row_start[node];
    const int end = row_start[node + 1];

    const float2* __restrict__ x2 = (const float2*)x;   // row = 64 float2
    float2 acc = make_float2(0.f, 0.f);

    for (int base = beg; base < end; base += 64) {
        const int m = min(64, end - base);
        int idx = 0;
        if (base + lane < end) idx = sorted_src[base + lane];  // coalesced

        int j = 0;
        for (; j + 4 <= m; j += 4) {
            int s0 = __shfl(idx, j + 0);
            int s1 = __shfl(idx, j + 1);
            int s2 = __shfl(idx, j + 2);
            int s3 = __shfl(idx, j + 3);
            float2 v0 = x2[(long long)s0 * 64 + lane];   // 4 independent
            float2 v1 = x2[(long long)s1 * 64 + lane];   // 512B row loads
            float2 v2 = x2[(long long)s2 * 64 + lane];   // in flight
            float2 v3 = x2[(long long)s3 * 64 + lane];
            acc.x += (v0.x + v1.x) + (v2.x + v3.x);
            acc.y += (v0.y + v1.y) + (v2.y + v3.y);
        }
        for (; j < m; ++j) {
            int s = __shfl(idx, j);
            float2 v = x2[(long long)s * 64 + lane];
            acc.x += v.x; acc.y += v.y;
        }
    }
    ((float2*)out)[(long long)node * 64 + lane] = acc;   // written exactly once
}

// ---- fallback (atomic version) if workspace is too small ----
__global__ void __launch_bounds__(256)
mp_scatter_add_kernel(const float* __restrict__ x,
                      const int* __restrict__ edge_dst,
                      const int* __restrict__ edge_src,
                      float* __restrict__ out, int n_edges) {
    long long tid = (long long)blockIdx.x * blockDim.x + threadIdx.x;
    long long total = (long long)n_edges * (DFEAT / 4);
    if (tid >= total) return;
    int e  = (int)(tid >> 5);
    int d4 = (int)(tid & 31);
    int src = edge_src[e];
    int dst = edge_dst[e];
    const float4 v = *reinterpret_cast<const float4*>(x + (long long)src * DFEAT + d4 * 4);
    float* o = out + (long long)dst * DFEAT + d4 * 4;
    atomicAdd(o + 0, v.x); atomicAdd(o + 1, v.y);
    atomicAdd(o + 2, v.z); atomicAdd(o + 3, v.w);
}

extern "C" void kernel_launch(void* const* d_in, const int* in_sizes, int n_in,
                              void* d_out, int out_size, void* d_ws, size_t ws_size,
                              hipStream_t stream) {
    const float* x        = (const float*)d_in[0];
    const int*   edge_idx = (const int*)d_in[1];

    const int N = in_sizes[0] / DFEAT;         // 50000
    const int E = in_sizes[1] / 2;             // 1600000
    const int* edge_dst = edge_idx;            // edge_index[0]
    const int* edge_src = edge_idx + E;        // edge_index[1]
    float* out = (float*)d_out;

    const int nscan = (N + 255) / 256;         // 196 scan blocks

    // Workspace (ints): row_start[N+1] | cursor[N] | blocksum[nscan] | sorted_src[E]
    const size_t need = (size_t)(2 * N + 2 + nscan + E) * sizeof(int);
    if (ws_size < need) {
        (void)hipMemsetAsync(out, 0, (size_t)out_size * sizeof(float), stream);
        const long long total = (long long)E * (DFEAT / 4);
        const long long grid = (total + 255) / 256;
        mp_scatter_add_kernel<<<(dim3)(unsigned)grid, 256, 0, stream>>>(
            x, edge_dst, edge_src, out, E);
        return;
    }

    int* row_start  = (int*)d_ws;              // N+1
    int* cursor     = row_start + (N + 1);     // N
    int* blocksum   = cursor + N;              // nscan
    int* sorted_src = blocksum + nscan;        // E

    (void)hipMemsetAsync(row_start, 0, (size_t)(N + 1) * sizeof(int), stream);

    hist_kernel         <<<2048, 256, 0, stream>>>(edge_dst, row_start, E);
    scan_partial_kernel <<<nscan, 256, 0, stream>>>(row_start, blocksum, N);
    scan_blocksum_kernel<<<1, 256, 0, stream>>>(blocksum, &row_start[N], nscan);
    scan_apply_kernel   <<<nscan, 256, 0, stream>>>(row_start, blocksum, cursor, N);
    scatter_kernel      <<<2048, 256, 0, stream>>>(edge_dst, edge_src, cursor, sorted_src, E);

    const int gather_blocks = (N + 3) / 4;     // 4 waves/block, 1 node/wave
    gather_kernel<<<gather_blocks, 256, 0, stream>>>(x, row_start, sorted_src, out, N);
}